// Round 8
// baseline (119.488 us; speedup 1.0000x reference)
//
#include <hip/hip_runtime.h>
#include <math.h>

// Problem shapes (fixed by setup_inputs)
#define BB 16
#define NN 16384
#define DD 256     // == O
#define NS1 128    // blocks per batch, pass 1 (xsum)
#define NS3 128    // blocks per batch, pass 2 (scores + flash partials)

typedef float floatx4 __attribute__((ext_vector_type(4)));

__device__ __forceinline__ floatx4 ntload4(const float* p) {
  return __builtin_nontemporal_load((const floatx4*)p);
}

// ---------------- K1: partial column-sums of x ----------------
// grid (NS1, BB), block 256 (4 waves). Each block streams 128 rows (128 KB);
// each wave owns a CONTIGUOUS 32-row span (DRAM page-friendly, mirrors k3).
__global__ __launch_bounds__(256) void k1_xsum_part(const float* __restrict__ x,
                                                    float* __restrict__ part) {
  const int b = blockIdx.y, blk = blockIdx.x;
  const int wave = threadIdx.x >> 6, lane = threadIdx.x & 63;
  const int rows = NN / NS1;  // 128
  const int r0 = wave * (rows / 4);
  const float* xp = x + ((size_t)b * NN + (size_t)blk * rows + r0) * DD + lane * 4;
  floatx4 acc0 = {0.f, 0.f, 0.f, 0.f};
  floatx4 acc1 = {0.f, 0.f, 0.f, 0.f};
#pragma unroll 4
  for (int r = 0; r < rows / 4; r += 2) {
    acc0 += ntload4(xp + (size_t)r * DD);
    acc1 += ntload4(xp + (size_t)(r + 1) * DD);
  }
  acc0 += acc1;
  __shared__ float sP[4][DD];
  *(floatx4*)&sP[wave][lane * 4] = acc0;
  __syncthreads();
  const int t = threadIdx.x;
  part[((size_t)b * NS1 + blk) * DD + t] = sP[0][t] + sP[1][t] + sP[2][t] + sP[3][t];
}

// ---------------- K2: part -> xsum -> ksum -> v, c ----------------
__global__ __launch_bounds__(256) void k2_prep(const float* __restrict__ part,
                                               const float* __restrict__ Wq,
                                               const float* __restrict__ bq,
                                               const float* __restrict__ Wk,
                                               const float* __restrict__ bk,
                                               float* __restrict__ v,
                                               float* __restrict__ c) {
  const int b = blockIdx.x, t = threadIdx.x;
  __shared__ float xs[DD];
  __shared__ float ks[DD];
  __shared__ float red[256];

  // 4 independent accumulators for ILP over the 128 partial tiles
  float a0 = 0.f, a1 = 0.f, a2 = 0.f, a3 = 0.f;
  const float* pb = part + (size_t)b * NS1 * DD + t;
#pragma unroll 4
  for (int blk = 0; blk < NS1; blk += 4) {
    a0 += pb[(size_t)(blk + 0) * DD];
    a1 += pb[(size_t)(blk + 1) * DD];
    a2 += pb[(size_t)(blk + 2) * DD];
    a3 += pb[(size_t)(blk + 3) * DD];
  }
  xs[t] = (a0 + a1) + (a2 + a3);
  __syncthreads();

  // ksum[o] = Wk[o,:] . xsum + N*bk[o]
  float kacc = (float)NN * bk[t];
  const float4* wkrow4 = (const float4*)(Wk + (size_t)t * DD);
#pragma unroll 4
  for (int j4 = 0; j4 < DD / 4; ++j4) {
    const float4 w = wkrow4[j4];
    kacc += w.x * xs[4 * j4] + w.y * xs[4 * j4 + 1] + w.z * xs[4 * j4 + 2] + w.w * xs[4 * j4 + 3];
  }
  ks[t] = kacc;
  __syncthreads();

  // v[d] = sum_o Wq[o,d] * ksum[o]  (coalesced over t)
  float vacc = 0.f;
  for (int o = 0; o < DD; ++o) vacc += Wq[(size_t)o * DD + t] * ks[o];
  v[b * DD + t] = vacc;

  // c = bq . ksum
  red[t] = bq[t] * ks[t];
  __syncthreads();
  for (int s = 128; s > 0; s >>= 1) {
    if (t < s) red[t] += red[t + s];
    __syncthreads();
  }
  if (t == 0) c[b] = red[0];
}

// ---------------- K3: main pass — scores + flash partials ----------------
__global__ __launch_bounds__(256) void k3_main(const float* __restrict__ x,
                                               const float* __restrict__ v,
                                               const float* __restrict__ c,
                                               float* __restrict__ scores,
                                               float* __restrict__ pm,
                                               float* __restrict__ pz,
                                               float* __restrict__ pP) {
  const int b = blockIdx.y, blk = blockIdx.x;
  const int wave = threadIdx.x >> 6, lane = threadIdx.x & 63;
  const float scale = 0.0625f;  // 1/sqrt(256)

  const floatx4 vl = *(const floatx4*)(v + b * DD + lane * 4);
  const float cb = c[b];
  const int rows_per_block = NN / NS3;          // 128
  const int rows_per_wave = rows_per_block / 4; // 32
  const int n0 = blk * rows_per_block + wave * rows_per_wave;
  const float* xb = x + (size_t)b * NN * DD;

  float m = -INFINITY, Z = 0.f;
  floatx4 P = {0.f, 0.f, 0.f, 0.f};

  for (int i = 0; i < rows_per_wave; ++i) {
    const int n = n0 + i;
    const floatx4 xr = ntload4(xb + (size_t)n * DD + lane * 4);
    const floatx4 prod = xr * vl;
    float dot = prod.x + prod.y + prod.z + prod.w;
#pragma unroll
    for (int off = 32; off >= 1; off >>= 1) dot += __shfl_xor(dot, off, 64);
    const float s = (dot + cb) * scale;
    if (lane == 0) scores[(size_t)b * NN + n] = s;
    // wave-uniform branch (s identical across lanes after butterfly)
    if (s > m) {            // rescale path (covers first iter: exp(-inf)=0)
      const float alpha = __expf(m - s);
      Z = Z * alpha + 1.f;
      P = P * alpha + xr;
      m = s;
    } else {                // common path
      const float e = __expf(s - m);
      Z += e;
      P += xr * e;
    }
  }

  // combine the 4 waves of this block
  __shared__ float sm[4], sz[4];
  __shared__ float sP[4][DD];
  *(floatx4*)&sP[wave][lane * 4] = P;
  if (lane == 0) { sm[wave] = m; sz[wave] = Z; }
  __syncthreads();

  const int t = threadIdx.x;
  const float M = fmaxf(fmaxf(sm[0], sm[1]), fmaxf(sm[2], sm[3]));
  const float e0 = __expf(sm[0] - M), e1 = __expf(sm[1] - M);
  const float e2 = __expf(sm[2] - M), e3 = __expf(sm[3] - M);
  const float Pd = sP[0][t] * e0 + sP[1][t] * e1 + sP[2][t] * e2 + sP[3][t] * e3;
  const size_t idx = (size_t)b * NS3 + blk;
  pP[idx * DD + t] = Pd;
  if (t == 0) {
    pm[idx] = M;
    pz[idx] = sz[0] * e0 + sz[1] * e1 + sz[2] * e2 + sz[3] * e3;
  }
}

// ---------------- K45: merged finalization ----------------
// Blocks 0..15 (role A): aggregated_feature[b].
// Blocks 16..79 (role B): average_customer_weights — each block redundantly
// recomputes all 16 (M_b, 1/Z_b) from pm/pz via 16-lane-group shuffle reduces.
__global__ __launch_bounds__(256) void k45_final(const float* __restrict__ pm,
                                                 const float* __restrict__ pz,
                                                 const float* __restrict__ pP,
                                                 const float* __restrict__ scores,
                                                 float* __restrict__ out_agg,
                                                 float* __restrict__ out_w) {
  const int t = threadIdx.x;
  if (blockIdx.x < BB) {
    // ---- role A ----
    const int b = blockIdx.x;
    __shared__ float red[256];
    const size_t base = (size_t)b * NS3;

    red[t] = (t < NS3) ? pm[base + t] : -INFINITY;
    __syncthreads();
    for (int s = 128; s > 0; s >>= 1) {
      if (t < s) red[t] = fmaxf(red[t], red[t + s]);
      __syncthreads();
    }
    const float M = red[0];
    __syncthreads();

    red[t] = (t < NS3) ? pz[base + t] * __expf(pm[base + t] - M) : 0.f;
    __syncthreads();
    for (int s = 128; s > 0; s >>= 1) {
      if (t < s) red[t] += red[t + s];
      __syncthreads();
    }
    const float rZ = 1.f / red[0];

    float acc = 0.f;
    for (int blk = 0; blk < NS3; ++blk)
      acc += pP[(base + blk) * DD + t] * __expf(pm[base + blk] - M);
    out_agg[b * DD + t] = acc * rZ;
  } else {
    // ---- role B ----
    const int wb = blockIdx.x - BB;
    __shared__ float sM[BB], sR[BB];
    const int b = t >> 4;
    const int i = t & 15;
    const size_t base = (size_t)b * NS3 + i * 8;

    float mloc = -INFINITY;
#pragma unroll
    for (int k = 0; k < 8; ++k) mloc = fmaxf(mloc, pm[base + k]);
#pragma unroll
    for (int off = 8; off >= 1; off >>= 1) mloc = fmaxf(mloc, __shfl_xor(mloc, off, 64));
    const float M = mloc;

    float zloc = 0.f;
#pragma unroll
    for (int k = 0; k < 8; ++k) zloc += pz[base + k] * __expf(pm[base + k] - M);
#pragma unroll
    for (int off = 8; off >= 1; off >>= 1) zloc += __shfl_xor(zloc, off, 64);

    if (i == 0) { sM[b] = M; sR[b] = 1.f / zloc; }
    __syncthreads();

    const int n = wb * 256 + t;
    float acc = 0.f;
#pragma unroll
    for (int bb = 0; bb < BB; ++bb)
      acc += __expf(scores[(size_t)bb * NN + n] - sM[bb]) * sR[bb];
    out_w[n] = acc * (1.f / BB);
  }
}

extern "C" void kernel_launch(void* const* d_in, const int* in_sizes, int n_in,
                              void* d_out, int out_size, void* d_ws, size_t ws_size,
                              hipStream_t stream) {
  const float* x  = (const float*)d_in[0];
  const float* Wq = (const float*)d_in[1];
  const float* bq = (const float*)d_in[2];
  const float* Wk = (const float*)d_in[3];
  const float* bk = (const float*)d_in[4];

  float* out  = (float*)d_out;
  float* agg  = out;             // [16, 256]
  float* avgw = out + BB * DD;   // [16384]

  float* ws = (float*)d_ws;
  float* part   = ws;  ws += (size_t)BB * NS1 * DD;  // 524288
  float* v      = ws;  ws += BB * DD;                // 4096
  float* c      = ws;  ws += BB;                     // 16
  float* scores = ws;  ws += (size_t)BB * NN;        // 262144
  float* pm     = ws;  ws += BB * NS3;               // 2048
  float* pz     = ws;  ws += BB * NS3;               // 2048
  float* pP     = ws;  ws += (size_t)BB * NS3 * DD;  // 524288

  k1_xsum_part<<<dim3(NS1, BB), 256, 0, stream>>>(x, part);
  k2_prep<<<BB, 256, 0, stream>>>(part, Wq, bq, Wk, bk, v, c);
  k3_main<<<dim3(NS3, BB), 256, 0, stream>>>(x, v, c, scores, pm, pz, pP);
  k45_final<<<BB + NN / 256, 256, 0, stream>>>(pm, pz, pP, scores, agg, avgw);
}

// Round 9
// 114.583 us; speedup vs baseline: 1.0428x; 1.0428x over previous
//
#include <hip/hip_runtime.h>
#include <math.h>

// Problem shapes (fixed by setup_inputs)
#define BB 16
#define NN 16384
#define DD 256     // == O
#define NS1 128    // blocks per batch, pass 1 (xsum)
#define NS3 128    // blocks per batch, pass 2 (scores + flash partials)

typedef float floatx4 __attribute__((ext_vector_type(4)));

__device__ __forceinline__ floatx4 ntload4(const float* p) {
  return __builtin_nontemporal_load((const floatx4*)p);
}

// ---------------- K1: partial column-sums of x (round-7 proven form) --------
// grid (NS1, BB), block 256 (4 waves). Wave w takes rows w, w+4, ... so the
// block's combined stream is a dense sequential window.
__global__ __launch_bounds__(256) void k1_xsum_part(const float* __restrict__ x,
                                                    float* __restrict__ part) {
  const int b = blockIdx.y, blk = blockIdx.x;
  const int wave = threadIdx.x >> 6, lane = threadIdx.x & 63;
  const int rows = NN / NS1;  // 128
  const float* xp = x + ((size_t)b * NN + (size_t)blk * rows) * DD;
  floatx4 acc = {0.f, 0.f, 0.f, 0.f};
  for (int r = wave; r < rows; r += 4) {
    acc += ntload4(xp + (size_t)r * DD + lane * 4);
  }
  __shared__ float sP[4][DD];
  *(floatx4*)&sP[wave][lane * 4] = acc;
  __syncthreads();
  const int t = threadIdx.x;
  part[((size_t)b * NS1 + blk) * DD + t] = sP[0][t] + sP[1][t] + sP[2][t] + sP[3][t];
}

// ---------------- K2: part -> xsum -> ksum -> v, c ----------------
// 16 blocks, latency-bound: 8 independent accumulators, fully unrolled,
// to keep ~8 loads in flight per thread through the strided part walk.
__global__ __launch_bounds__(256) void k2_prep(const float* __restrict__ part,
                                               const float* __restrict__ Wq,
                                               const float* __restrict__ bq,
                                               const float* __restrict__ Wk,
                                               const float* __restrict__ bk,
                                               float* __restrict__ v,
                                               float* __restrict__ c) {
  const int b = blockIdx.x, t = threadIdx.x;
  __shared__ float xs[DD];
  __shared__ float ks[DD];
  __shared__ float red[256];

  const float* pb = part + (size_t)b * NS1 * DD + t;
  float a[8];
#pragma unroll
  for (int u = 0; u < 8; ++u) a[u] = 0.f;
#pragma unroll
  for (int blk = 0; blk < NS1; blk += 8) {
#pragma unroll
    for (int u = 0; u < 8; ++u) a[u] += pb[(size_t)(blk + u) * DD];
  }
  xs[t] = ((a[0] + a[1]) + (a[2] + a[3])) + ((a[4] + a[5]) + (a[6] + a[7]));
  __syncthreads();

  // ksum[o] = Wk[o,:] . xsum + N*bk[o]
  float kacc = (float)NN * bk[t];
  const float4* wkrow4 = (const float4*)(Wk + (size_t)t * DD);
#pragma unroll 4
  for (int j4 = 0; j4 < DD / 4; ++j4) {
    const float4 w = wkrow4[j4];
    kacc += w.x * xs[4 * j4] + w.y * xs[4 * j4 + 1] + w.z * xs[4 * j4 + 2] + w.w * xs[4 * j4 + 3];
  }
  ks[t] = kacc;
  __syncthreads();

  // v[d] = sum_o Wq[o,d] * ksum[o]  (coalesced over t)
  float vacc = 0.f;
  for (int o = 0; o < DD; ++o) vacc += Wq[(size_t)o * DD + t] * ks[o];
  v[b * DD + t] = vacc;

  // c = bq . ksum
  red[t] = bq[t] * ks[t];
  __syncthreads();
  for (int s = 128; s > 0; s >>= 1) {
    if (t < s) red[t] += red[t + s];
    __syncthreads();
  }
  if (t == 0) c[b] = red[0];
}

// ---------------- K3: main pass — scores + flash partials (round-7 form) ----
__global__ __launch_bounds__(256) void k3_main(const float* __restrict__ x,
                                               const float* __restrict__ v,
                                               const float* __restrict__ c,
                                               float* __restrict__ scores,
                                               float* __restrict__ pm,
                                               float* __restrict__ pz,
                                               float* __restrict__ pP) {
  const int b = blockIdx.y, blk = blockIdx.x;
  const int wave = threadIdx.x >> 6, lane = threadIdx.x & 63;
  const float scale = 0.0625f;  // 1/sqrt(256)

  const floatx4 vl = *(const floatx4*)(v + b * DD + lane * 4);
  const float cb = c[b];
  const int rows_per_block = NN / NS3;          // 128
  const int rows_per_wave = rows_per_block / 4; // 32
  const int n0 = blk * rows_per_block + wave * rows_per_wave;
  const float* xb = x + (size_t)b * NN * DD;

  float m = -INFINITY, Z = 0.f;
  floatx4 P = {0.f, 0.f, 0.f, 0.f};

  for (int i = 0; i < rows_per_wave; ++i) {
    const int n = n0 + i;
    const floatx4 xr = ntload4(xb + (size_t)n * DD + lane * 4);
    const floatx4 prod = xr * vl;
    float dot = prod.x + prod.y + prod.z + prod.w;
#pragma unroll
    for (int off = 32; off >= 1; off >>= 1) dot += __shfl_xor(dot, off, 64);
    const float s = (dot + cb) * scale;
    if (lane == 0) scores[(size_t)b * NN + n] = s;
    // wave-uniform branch (s identical across lanes after butterfly)
    if (s > m) {            // rescale path (covers first iter: exp(-inf)=0)
      const float alpha = __expf(m - s);
      Z = Z * alpha + 1.f;
      P = P * alpha + xr;
      m = s;
    } else {                // common path
      const float e = __expf(s - m);
      Z += e;
      P += xr * e;
    }
  }

  // combine the 4 waves of this block
  __shared__ float sm[4], sz[4];
  __shared__ float sP[4][DD];
  *(floatx4*)&sP[wave][lane * 4] = P;
  if (lane == 0) { sm[wave] = m; sz[wave] = Z; }
  __syncthreads();

  const int t = threadIdx.x;
  const float M = fmaxf(fmaxf(sm[0], sm[1]), fmaxf(sm[2], sm[3]));
  const float e0 = __expf(sm[0] - M), e1 = __expf(sm[1] - M);
  const float e2 = __expf(sm[2] - M), e3 = __expf(sm[3] - M);
  const float Pd = sP[0][t] * e0 + sP[1][t] * e1 + sP[2][t] * e2 + sP[3][t] * e3;
  const size_t idx = (size_t)b * NS3 + blk;
  pP[idx * DD + t] = Pd;
  if (t == 0) {
    pm[idx] = M;
    pz[idx] = sz[0] * e0 + sz[1] * e1 + sz[2] * e2 + sz[3] * e3;
  }
}

// ---------------- K45: merged finalization ----------------
__global__ __launch_bounds__(256) void k45_final(const float* __restrict__ pm,
                                                 const float* __restrict__ pz,
                                                 const float* __restrict__ pP,
                                                 const float* __restrict__ scores,
                                                 float* __restrict__ out_agg,
                                                 float* __restrict__ out_w) {
  const int t = threadIdx.x;
  if (blockIdx.x < BB) {
    // ---- role A: aggregated_feature[b] ----
    const int b = blockIdx.x;
    __shared__ float red[256];
    const size_t base = (size_t)b * NS3;

    red[t] = (t < NS3) ? pm[base + t] : -INFINITY;
    __syncthreads();
    for (int s = 128; s > 0; s >>= 1) {
      if (t < s) red[t] = fmaxf(red[t], red[t + s]);
      __syncthreads();
    }
    const float M = red[0];
    __syncthreads();

    red[t] = (t < NS3) ? pz[base + t] * __expf(pm[base + t] - M) : 0.f;
    __syncthreads();
    for (int s = 128; s > 0; s >>= 1) {
      if (t < s) red[t] += red[t + s];
      __syncthreads();
    }
    const float rZ = 1.f / red[0];

    float acc = 0.f;
    for (int blk = 0; blk < NS3; ++blk)
      acc += pP[(base + blk) * DD + t] * __expf(pm[base + blk] - M);
    out_agg[b * DD + t] = acc * rZ;
  } else {
    // ---- role B: average_customer_weights ----
    const int wb = blockIdx.x - BB;
    __shared__ float sM[BB], sR[BB];
    const int b = t >> 4;
    const int i = t & 15;
    const size_t base = (size_t)b * NS3 + i * 8;

    float mloc = -INFINITY;
#pragma unroll
    for (int k = 0; k < 8; ++k) mloc = fmaxf(mloc, pm[base + k]);
#pragma unroll
    for (int off = 8; off >= 1; off >>= 1) mloc = fmaxf(mloc, __shfl_xor(mloc, off, 64));
    const float M = mloc;

    float zloc = 0.f;
#pragma unroll
    for (int k = 0; k < 8; ++k) zloc += pz[base + k] * __expf(pm[base + k] - M);
#pragma unroll
    for (int off = 8; off >= 1; off >>= 1) zloc += __shfl_xor(zloc, off, 64);

    if (i == 0) { sM[b] = M; sR[b] = 1.f / zloc; }
    __syncthreads();

    const int n = wb * 256 + t;
    float acc = 0.f;
#pragma unroll
    for (int bb = 0; bb < BB; ++bb)
      acc += __expf(scores[(size_t)bb * NN + n] - sM[bb]) * sR[bb];
    out_w[n] = acc * (1.f / BB);
  }
}

extern "C" void kernel_launch(void* const* d_in, const int* in_sizes, int n_in,
                              void* d_out, int out_size, void* d_ws, size_t ws_size,
                              hipStream_t stream) {
  const float* x  = (const float*)d_in[0];
  const float* Wq = (const float*)d_in[1];
  const float* bq = (const float*)d_in[2];
  const float* Wk = (const float*)d_in[3];
  const float* bk = (const float*)d_in[4];

  float* out  = (float*)d_out;
  float* agg  = out;             // [16, 256]
  float* avgw = out + BB * DD;   // [16384]

  float* ws = (float*)d_ws;
  float* part   = ws;  ws += (size_t)BB * NS1 * DD;  // 524288
  float* v      = ws;  ws += BB * DD;                // 4096
  float* c      = ws;  ws += BB;                     // 16
  float* scores = ws;  ws += (size_t)BB * NN;        // 262144
  float* pm     = ws;  ws += BB * NS3;               // 2048
  float* pz     = ws;  ws += BB * NS3;               // 2048
  float* pP     = ws;  ws += (size_t)BB * NS3 * DD;  // 524288

  k1_xsum_part<<<dim3(NS1, BB), 256, 0, stream>>>(x, part);
  k2_prep<<<BB, 256, 0, stream>>>(part, Wq, bq, Wk, bk, v, c);
  k3_main<<<dim3(NS3, BB), 256, 0, stream>>>(x, v, c, scores, pm, pz, pP);
  k45_final<<<BB + NN / 256, 256, 0, stream>>>(pm, pz, pP, scores, agg, avgw);
}

// Round 10
// 113.650 us; speedup vs baseline: 1.0514x; 1.0082x over previous
//
#include <hip/hip_runtime.h>
#include <math.h>

// Problem shapes (fixed by setup_inputs)
#define BB 16
#define NN 16384
#define DD 256     // == O
#define NS1 128    // blocks per batch, pass 1 (xsum)
#define NS3 128    // blocks per batch, pass 2 (scores + flash partials)

typedef float floatx4 __attribute__((ext_vector_type(4)));

__device__ __forceinline__ floatx4 ntload4(const float* p) {
  return __builtin_nontemporal_load((const floatx4*)p);
}

// ---------------- K1: partial column-sums of x (round-7 proven form) --------
// grid (NS1, BB), block 256 (4 waves). Wave w takes rows w, w+4, ... so the
// block's combined stream is a dense sequential window.
__global__ __launch_bounds__(256) void k1_xsum_part(const float* __restrict__ x,
                                                    float* __restrict__ part) {
  const int b = blockIdx.y, blk = blockIdx.x;
  const int wave = threadIdx.x >> 6, lane = threadIdx.x & 63;
  const int rows = NN / NS1;  // 128
  const float* xp = x + ((size_t)b * NN + (size_t)blk * rows) * DD;
  floatx4 acc = {0.f, 0.f, 0.f, 0.f};
  for (int r = wave; r < rows; r += 4) {
    acc += ntload4(xp + (size_t)r * DD + lane * 4);
  }
  __shared__ float sP[4][DD];
  *(floatx4*)&sP[wave][lane * 4] = acc;
  __syncthreads();
  const int t = threadIdx.x;
  part[((size_t)b * NS1 + blk) * DD + t] = sP[0][t] + sP[1][t] + sP[2][t] + sP[3][t];
}

// ---------------- K2: part -> xsum -> ksum -> v, c (1024 threads) ----------
// Group g = t>>8 (4 groups) parallelizes every serial walk 4x:
//   part-walk: 32 tiles/group with 8-deep ILP -> 4 latency rounds
//   ksum/v matvecs: 64-length partial dots, LDS-combined.
__global__ __launch_bounds__(1024) void k2_prep(const float* __restrict__ part,
                                                const float* __restrict__ Wq,
                                                const float* __restrict__ bq,
                                                const float* __restrict__ Wk,
                                                const float* __restrict__ bk,
                                                float* __restrict__ v,
                                                float* __restrict__ c) {
  const int b = blockIdx.x, t = threadIdx.x;
  const int d = t & 255;   // doubles as output index o
  const int g = t >> 8;    // 0..3
  __shared__ float stage[4][DD];
  __shared__ float xs[DD];
  __shared__ float ks[DD];
  __shared__ float red[256];

  // ---- part walk: tiles [g*32, g*32+32), 8 accumulators ----
  const float* pb = part + (size_t)b * NS1 * DD + d;
  float a[8];
#pragma unroll
  for (int u = 0; u < 8; ++u) a[u] = 0.f;
#pragma unroll
  for (int blk = 0; blk < 32; blk += 8) {
#pragma unroll
    for (int u = 0; u < 8; ++u) a[u] += pb[(size_t)(g * 32 + blk + u) * DD];
  }
  stage[g][d] = ((a[0] + a[1]) + (a[2] + a[3])) + ((a[4] + a[5]) + (a[6] + a[7]));
  __syncthreads();
  if (g == 0) xs[d] = (stage[0][d] + stage[1][d]) + (stage[2][d] + stage[3][d]);
  __syncthreads();

  // ---- ksum[o] partials: group g covers j in [g*64, g*64+64) ----
  float kp = 0.f;
  const float4* wk4 = (const float4*)(Wk + (size_t)d * DD + g * 64);
#pragma unroll 4
  for (int j4 = 0; j4 < 16; ++j4) {
    const float4 w = wk4[j4];
    const int j = g * 64 + 4 * j4;
    kp += w.x * xs[j] + w.y * xs[j + 1] + w.z * xs[j + 2] + w.w * xs[j + 3];
  }
  stage[g][d] = kp;
  __syncthreads();
  if (g == 0)
    ks[d] = (stage[0][d] + stage[1][d]) + (stage[2][d] + stage[3][d]) + (float)NN * bk[d];
  __syncthreads();

  // ---- v[d] partials: group g covers o in [g*64, g*64+64) ----
  float vp = 0.f;
#pragma unroll 4
  for (int o = 0; o < 64; ++o)
    vp += Wq[(size_t)(g * 64 + o) * DD + d] * ks[g * 64 + o];
  stage[g][d] = vp;
  __syncthreads();
  if (g == 0) {
    v[b * DD + d] = (stage[0][d] + stage[1][d]) + (stage[2][d] + stage[3][d]);
    red[d] = bq[d] * ks[d];
  }
  __syncthreads();
  for (int s = 128; s > 0; s >>= 1) {
    if (t < s) red[t] += red[t + s];
    __syncthreads();
  }
  if (t == 0) c[b] = red[0];
}

// ---------------- K3: main pass — 4-row batched flash ----------------
__global__ __launch_bounds__(256) void k3_main(const float* __restrict__ x,
                                               const float* __restrict__ v,
                                               const float* __restrict__ c,
                                               float* __restrict__ scores,
                                               float* __restrict__ pm,
                                               float* __restrict__ pz,
                                               float* __restrict__ pP) {
  const int b = blockIdx.y, blk = blockIdx.x;
  const int wave = threadIdx.x >> 6, lane = threadIdx.x & 63;
  const float scale = 0.0625f;  // 1/sqrt(256)

  const floatx4 vl = *(const floatx4*)(v + b * DD + lane * 4);
  const float cb = c[b];
  const int rows_per_block = NN / NS3;          // 128
  const int rows_per_wave = rows_per_block / 4; // 32
  const int n0 = blk * rows_per_block + wave * rows_per_wave;
  const float* xb = x + (size_t)b * NN * DD;

  float m = -INFINITY, Z = 0.f;
  floatx4 P = {0.f, 0.f, 0.f, 0.f};

#define DOT_OF(XR) ({ const floatx4 _p = (XR) * vl; _p.x + _p.y + _p.z + _p.w; })

  for (int i = 0; i < rows_per_wave; i += 4) {
    const float* base = xb + (size_t)(n0 + i) * DD + lane * 4;
    const floatx4 xr0 = ntload4(base);
    const floatx4 xr1 = ntload4(base + DD);
    const floatx4 xr2 = ntload4(base + 2 * DD);
    const floatx4 xr3 = ntload4(base + 3 * DD);
    float d0 = DOT_OF(xr0), d1 = DOT_OF(xr1), d2 = DOT_OF(xr2), d3 = DOT_OF(xr3);
#pragma unroll
    for (int off = 32; off >= 1; off >>= 1) {  // 4 independent butterfly chains
      d0 += __shfl_xor(d0, off, 64);
      d1 += __shfl_xor(d1, off, 64);
      d2 += __shfl_xor(d2, off, 64);
      d3 += __shfl_xor(d3, off, 64);
    }
    const float s0 = (d0 + cb) * scale, s1 = (d1 + cb) * scale;
    const float s2 = (d2 + cb) * scale, s3 = (d3 + cb) * scale;
    if (lane == 0) {
      floatx4 sv = {s0, s1, s2, s3};
      *(floatx4*)(scores + (size_t)b * NN + n0 + i) = sv;
    }
    // sequential online-softmax updates (wave-uniform branches)
#define SM_UPDATE(S, XR)                                   \
    if ((S) > m) {                                         \
      const float alpha = __expf(m - (S));                 \
      Z = Z * alpha + 1.f;                                 \
      P = P * alpha + (XR);                                \
      m = (S);                                             \
    } else {                                               \
      const float e = __expf((S) - m);                     \
      Z += e;                                              \
      P += (XR) * e;                                       \
    }
    SM_UPDATE(s0, xr0)
    SM_UPDATE(s1, xr1)
    SM_UPDATE(s2, xr2)
    SM_UPDATE(s3, xr3)
#undef SM_UPDATE
  }

  // combine the 4 waves of this block
  __shared__ float sm[4], sz[4];
  __shared__ float sP[4][DD];
  *(floatx4*)&sP[wave][lane * 4] = P;
  if (lane == 0) { sm[wave] = m; sz[wave] = Z; }
  __syncthreads();

  const int t = threadIdx.x;
  const float M = fmaxf(fmaxf(sm[0], sm[1]), fmaxf(sm[2], sm[3]));
  const float e0 = __expf(sm[0] - M), e1 = __expf(sm[1] - M);
  const float e2 = __expf(sm[2] - M), e3 = __expf(sm[3] - M);
  const float Pd = sP[0][t] * e0 + sP[1][t] * e1 + sP[2][t] * e2 + sP[3][t] * e3;
  const size_t idx = (size_t)b * NS3 + blk;
  pP[idx * DD + t] = Pd;
  if (t == 0) {
    pm[idx] = M;
    pz[idx] = sz[0] * e0 + sz[1] * e1 + sz[2] * e2 + sz[3] * e3;
  }
}

// ---------------- K45: merged finalization ----------------
__global__ __launch_bounds__(256) void k45_final(const float* __restrict__ pm,
                                                 const float* __restrict__ pz,
                                                 const float* __restrict__ pP,
                                                 const float* __restrict__ scores,
                                                 float* __restrict__ out_agg,
                                                 float* __restrict__ out_w) {
  const int t = threadIdx.x;
  if (blockIdx.x < BB) {
    // ---- role A: aggregated_feature[b] ----
    const int b = blockIdx.x;
    __shared__ float red[256];
    const size_t base = (size_t)b * NS3;

    red[t] = (t < NS3) ? pm[base + t] : -INFINITY;
    __syncthreads();
    for (int s = 128; s > 0; s >>= 1) {
      if (t < s) red[t] = fmaxf(red[t], red[t + s]);
      __syncthreads();
    }
    const float M = red[0];
    __syncthreads();

    red[t] = (t < NS3) ? pz[base + t] * __expf(pm[base + t] - M) : 0.f;
    __syncthreads();
    for (int s = 128; s > 0; s >>= 1) {
      if (t < s) red[t] += red[t + s];
      __syncthreads();
    }
    const float rZ = 1.f / red[0];

    float acc = 0.f;
    for (int blk = 0; blk < NS3; ++blk)
      acc += pP[(base + blk) * DD + t] * __expf(pm[base + blk] - M);
    out_agg[b * DD + t] = acc * rZ;
  } else {
    // ---- role B: average_customer_weights ----
    const int wb = blockIdx.x - BB;
    __shared__ float sM[BB], sR[BB];
    const int b = t >> 4;
    const int i = t & 15;
    const size_t base = (size_t)b * NS3 + i * 8;

    float mloc = -INFINITY;
#pragma unroll
    for (int k = 0; k < 8; ++k) mloc = fmaxf(mloc, pm[base + k]);
#pragma unroll
    for (int off = 8; off >= 1; off >>= 1) mloc = fmaxf(mloc, __shfl_xor(mloc, off, 64));
    const float M = mloc;

    float zloc = 0.f;
#pragma unroll
    for (int k = 0; k < 8; ++k) zloc += pz[base + k] * __expf(pm[base + k] - M);
#pragma unroll
    for (int off = 8; off >= 1; off >>= 1) zloc += __shfl_xor(zloc, off, 64);

    if (i == 0) { sM[b] = M; sR[b] = 1.f / zloc; }
    __syncthreads();

    const int n = wb * 256 + t;
    float acc = 0.f;
#pragma unroll
    for (int bb = 0; bb < BB; ++bb)
      acc += __expf(scores[(size_t)bb * NN + n] - sM[bb]) * sR[bb];
    out_w[n] = acc * (1.f / BB);
  }
}

extern "C" void kernel_launch(void* const* d_in, const int* in_sizes, int n_in,
                              void* d_out, int out_size, void* d_ws, size_t ws_size,
                              hipStream_t stream) {
  const float* x  = (const float*)d_in[0];
  const float* Wq = (const float*)d_in[1];
  const float* bq = (const float*)d_in[2];
  const float* Wk = (const float*)d_in[3];
  const float* bk = (const float*)d_in[4];

  float* out  = (float*)d_out;
  float* agg  = out;             // [16, 256]
  float* avgw = out + BB * DD;   // [16384]

  float* ws = (float*)d_ws;
  float* part   = ws;  ws += (size_t)BB * NS1 * DD;  // 524288
  float* v      = ws;  ws += BB * DD;                // 4096
  float* c      = ws;  ws += BB;                     // 16
  float* scores = ws;  ws += (size_t)BB * NN;        // 262144
  float* pm     = ws;  ws += BB * NS3;               // 2048
  float* pz     = ws;  ws += BB * NS3;               // 2048
  float* pP     = ws;  ws += (size_t)BB * NS3 * DD;  // 524288

  k1_xsum_part<<<dim3(NS1, BB), 256, 0, stream>>>(x, part);
  k2_prep<<<BB, 1024, 0, stream>>>(part, Wq, bq, Wk, bk, v, c);
  k3_main<<<dim3(NS3, BB), 256, 0, stream>>>(x, v, c, scores, pm, pz, pP);
  k45_final<<<BB + NN / 256, 256, 0, stream>>>(pm, pz, pP, scores, agg, avgw);
}

// Round 11
// 111.991 us; speedup vs baseline: 1.0669x; 1.0148x over previous
//
#include <hip/hip_runtime.h>
#include <math.h>

// Problem shapes (fixed by setup_inputs)
#define BB 16
#define NN 16384
#define DD 256     // == O
#define NS1 128    // blocks per batch, pass 1 (xsum)
#define NS3 128    // blocks per batch, pass 2 (scores + flash partials)

typedef float floatx4 __attribute__((ext_vector_type(4)));

__device__ __forceinline__ floatx4 ntload4(const float* p) {
  return __builtin_nontemporal_load((const floatx4*)p);
}

// ---------------- K1: partial column-sums of x ----------------
// grid (NS1, BB), block 256 (4 waves). Wave w takes rows w, w+4, ... (proven
// round-7 traversal) — now with 4 independent accumulators for load ILP.
__global__ __launch_bounds__(256) void k1_xsum_part(const float* __restrict__ x,
                                                    float* __restrict__ part) {
  const int b = blockIdx.y, blk = blockIdx.x;
  const int wave = threadIdx.x >> 6, lane = threadIdx.x & 63;
  const int rows = NN / NS1;  // 128
  const float* xp = x + ((size_t)b * NN + (size_t)blk * rows + wave) * DD + lane * 4;
  floatx4 a0 = {0.f, 0.f, 0.f, 0.f};
  floatx4 a1 = {0.f, 0.f, 0.f, 0.f};
  floatx4 a2 = {0.f, 0.f, 0.f, 0.f};
  floatx4 a3 = {0.f, 0.f, 0.f, 0.f};
#pragma unroll
  for (int r = 0; r < rows; r += 16) {   // wave's rows: wave + {0,4,8,12} + 16k
    a0 += ntload4(xp + (size_t)(r + 0) * DD);
    a1 += ntload4(xp + (size_t)(r + 4) * DD);
    a2 += ntload4(xp + (size_t)(r + 8) * DD);
    a3 += ntload4(xp + (size_t)(r + 12) * DD);
  }
  const floatx4 acc = (a0 + a1) + (a2 + a3);
  __shared__ float sP[4][DD];
  *(floatx4*)&sP[wave][lane * 4] = acc;
  __syncthreads();
  const int t = threadIdx.x;
  part[((size_t)b * NS1 + blk) * DD + t] = sP[0][t] + sP[1][t] + sP[2][t] + sP[3][t];
}

// ---------------- K2: part -> xsum -> ksum -> v, c (1024 threads) ----------
__global__ __launch_bounds__(1024) void k2_prep(const float* __restrict__ part,
                                                const float* __restrict__ Wq,
                                                const float* __restrict__ bq,
                                                const float* __restrict__ Wk,
                                                const float* __restrict__ bk,
                                                float* __restrict__ v,
                                                float* __restrict__ c) {
  const int b = blockIdx.x, t = threadIdx.x;
  const int d = t & 255;   // doubles as output index o
  const int g = t >> 8;    // 0..3
  __shared__ float stage[4][DD];
  __shared__ float xs[DD];
  __shared__ float ks[DD];
  __shared__ float red[256];

  // ---- part walk: tiles [g*32, g*32+32), 8 accumulators ----
  const float* pb = part + (size_t)b * NS1 * DD + d;
  float a[8];
#pragma unroll
  for (int u = 0; u < 8; ++u) a[u] = 0.f;
#pragma unroll
  for (int blk = 0; blk < 32; blk += 8) {
#pragma unroll
    for (int u = 0; u < 8; ++u) a[u] += pb[(size_t)(g * 32 + blk + u) * DD];
  }
  stage[g][d] = ((a[0] + a[1]) + (a[2] + a[3])) + ((a[4] + a[5]) + (a[6] + a[7]));
  __syncthreads();
  if (g == 0) xs[d] = (stage[0][d] + stage[1][d]) + (stage[2][d] + stage[3][d]);
  __syncthreads();

  // ---- ksum[o] partials: group g covers j in [g*64, g*64+64) ----
  float kp = 0.f;
  const float4* wk4 = (const float4*)(Wk + (size_t)d * DD + g * 64);
#pragma unroll 4
  for (int j4 = 0; j4 < 16; ++j4) {
    const float4 w = wk4[j4];
    const int j = g * 64 + 4 * j4;
    kp += w.x * xs[j] + w.y * xs[j + 1] + w.z * xs[j + 2] + w.w * xs[j + 3];
  }
  stage[g][d] = kp;
  __syncthreads();
  if (g == 0)
    ks[d] = (stage[0][d] + stage[1][d]) + (stage[2][d] + stage[3][d]) + (float)NN * bk[d];
  __syncthreads();

  // ---- v[d] partials: group g covers o in [g*64, g*64+64) ----
  float vp = 0.f;
#pragma unroll 4
  for (int o = 0; o < 64; ++o)
    vp += Wq[(size_t)(g * 64 + o) * DD + d] * ks[g * 64 + o];
  stage[g][d] = vp;
  __syncthreads();
  if (g == 0) {
    v[b * DD + d] = (stage[0][d] + stage[1][d]) + (stage[2][d] + stage[3][d]);
    red[d] = bq[d] * ks[d];
  }
  __syncthreads();
  for (int s = 128; s > 0; s >>= 1) {
    if (t < s) red[t] += red[t + s];
    __syncthreads();
  }
  if (t == 0) c[b] = red[0];
}

// ---------------- K3: main pass — 4-row batched flash ----------------
__global__ __launch_bounds__(256) void k3_main(const float* __restrict__ x,
                                               const float* __restrict__ v,
                                               const float* __restrict__ c,
                                               float* __restrict__ scores,
                                               float* __restrict__ pm,
                                               float* __restrict__ pz,
                                               float* __restrict__ pP) {
  const int b = blockIdx.y, blk = blockIdx.x;
  const int wave = threadIdx.x >> 6, lane = threadIdx.x & 63;
  const float scale = 0.0625f;  // 1/sqrt(256)

  const floatx4 vl = *(const floatx4*)(v + b * DD + lane * 4);
  const float cb = c[b];
  const int rows_per_block = NN / NS3;          // 128
  const int rows_per_wave = rows_per_block / 4; // 32
  const int n0 = blk * rows_per_block + wave * rows_per_wave;
  const float* xb = x + (size_t)b * NN * DD;

  float m = -INFINITY, Z = 0.f;
  floatx4 P = {0.f, 0.f, 0.f, 0.f};

#define DOT_OF(XR) ({ const floatx4 _p = (XR) * vl; _p.x + _p.y + _p.z + _p.w; })

  for (int i = 0; i < rows_per_wave; i += 4) {
    const float* base = xb + (size_t)(n0 + i) * DD + lane * 4;
    const floatx4 xr0 = ntload4(base);
    const floatx4 xr1 = ntload4(base + DD);
    const floatx4 xr2 = ntload4(base + 2 * DD);
    const floatx4 xr3 = ntload4(base + 3 * DD);
    float d0 = DOT_OF(xr0), d1 = DOT_OF(xr1), d2 = DOT_OF(xr2), d3 = DOT_OF(xr3);
#pragma unroll
    for (int off = 32; off >= 1; off >>= 1) {  // 4 independent butterfly chains
      d0 += __shfl_xor(d0, off, 64);
      d1 += __shfl_xor(d1, off, 64);
      d2 += __shfl_xor(d2, off, 64);
      d3 += __shfl_xor(d3, off, 64);
    }
    const float s0 = (d0 + cb) * scale, s1 = (d1 + cb) * scale;
    const float s2 = (d2 + cb) * scale, s3 = (d3 + cb) * scale;
    if (lane == 0) {
      floatx4 sv = {s0, s1, s2, s3};
      *(floatx4*)(scores + (size_t)b * NN + n0 + i) = sv;
    }
    // sequential online-softmax updates (wave-uniform branches)
#define SM_UPDATE(S, XR)                                   \
    if ((S) > m) {                                         \
      const float alpha = __expf(m - (S));                 \
      Z = Z * alpha + 1.f;                                 \
      P = P * alpha + (XR);                                \
      m = (S);                                             \
    } else {                                               \
      const float e = __expf((S) - m);                     \
      Z += e;                                              \
      P += (XR) * e;                                       \
    }
    SM_UPDATE(s0, xr0)
    SM_UPDATE(s1, xr1)
    SM_UPDATE(s2, xr2)
    SM_UPDATE(s3, xr3)
#undef SM_UPDATE
  }

  // combine the 4 waves of this block
  __shared__ float sm[4], sz[4];
  __shared__ float sP[4][DD];
  *(floatx4*)&sP[wave][lane * 4] = P;
  if (lane == 0) { sm[wave] = m; sz[wave] = Z; }
  __syncthreads();

  const int t = threadIdx.x;
  const float M = fmaxf(fmaxf(sm[0], sm[1]), fmaxf(sm[2], sm[3]));
  const float e0 = __expf(sm[0] - M), e1 = __expf(sm[1] - M);
  const float e2 = __expf(sm[2] - M), e3 = __expf(sm[3] - M);
  const float Pd = sP[0][t] * e0 + sP[1][t] * e1 + sP[2][t] * e2 + sP[3][t] * e3;
  const size_t idx = (size_t)b * NS3 + blk;
  pP[idx * DD + t] = Pd;
  if (t == 0) {
    pm[idx] = M;
    pz[idx] = sz[0] * e0 + sz[1] * e1 + sz[2] * e2 + sz[3] * e3;
  }
}

// ---------------- K45: merged finalization ----------------
__global__ __launch_bounds__(256) void k45_final(const float* __restrict__ pm,
                                                 const float* __restrict__ pz,
                                                 const float* __restrict__ pP,
                                                 const float* __restrict__ scores,
                                                 float* __restrict__ out_agg,
                                                 float* __restrict__ out_w) {
  const int t = threadIdx.x;
  if (blockIdx.x < BB) {
    // ---- role A: aggregated_feature[b] ----
    const int b = blockIdx.x;
    __shared__ float red[256];
    const size_t base = (size_t)b * NS3;

    red[t] = (t < NS3) ? pm[base + t] : -INFINITY;
    __syncthreads();
    for (int s = 128; s > 0; s >>= 1) {
      if (t < s) red[t] = fmaxf(red[t], red[t + s]);
      __syncthreads();
    }
    const float M = red[0];
    __syncthreads();

    red[t] = (t < NS3) ? pz[base + t] * __expf(pm[base + t] - M) : 0.f;
    __syncthreads();
    for (int s = 128; s > 0; s >>= 1) {
      if (t < s) red[t] += red[t + s];
      __syncthreads();
    }
    const float rZ = 1.f / red[0];

    float acc = 0.f;
    for (int blk = 0; blk < NS3; ++blk)
      acc += pP[(base + blk) * DD + t] * __expf(pm[base + blk] - M);
    out_agg[b * DD + t] = acc * rZ;
  } else {
    // ---- role B: average_customer_weights ----
    const int wb = blockIdx.x - BB;
    __shared__ float sM[BB], sR[BB];
    const int b = t >> 4;
    const int i = t & 15;
    const size_t base = (size_t)b * NS3 + i * 8;

    float mloc = -INFINITY;
#pragma unroll
    for (int k = 0; k < 8; ++k) mloc = fmaxf(mloc, pm[base + k]);
#pragma unroll
    for (int off = 8; off >= 1; off >>= 1) mloc = fmaxf(mloc, __shfl_xor(mloc, off, 64));
    const float M = mloc;

    float zloc = 0.f;
#pragma unroll
    for (int k = 0; k < 8; ++k) zloc += pz[base + k] * __expf(pm[base + k] - M);
#pragma unroll
    for (int off = 8; off >= 1; off >>= 1) zloc += __shfl_xor(zloc, off, 64);

    if (i == 0) { sM[b] = M; sR[b] = 1.f / zloc; }
    __syncthreads();

    const int n = wb * 256 + t;
    float acc = 0.f;
#pragma unroll
    for (int bb = 0; bb < BB; ++bb)
      acc += __expf(scores[(size_t)bb * NN + n] - sM[bb]) * sR[bb];
    out_w[n] = acc * (1.f / BB);
  }
}

extern "C" void kernel_launch(void* const* d_in, const int* in_sizes, int n_in,
                              void* d_out, int out_size, void* d_ws, size_t ws_size,
                              hipStream_t stream) {
  const float* x  = (const float*)d_in[0];
  const float* Wq = (const float*)d_in[1];
  const float* bq = (const float*)d_in[2];
  const float* Wk = (const float*)d_in[3];
  const float* bk = (const float*)d_in[4];

  float* out  = (float*)d_out;
  float* agg  = out;             // [16, 256]
  float* avgw = out + BB * DD;   // [16384]

  float* ws = (float*)d_ws;
  float* part   = ws;  ws += (size_t)BB * NS1 * DD;  // 524288
  float* v      = ws;  ws += BB * DD;                // 4096
  float* c      = ws;  ws += BB;                     // 16
  float* scores = ws;  ws += (size_t)BB * NN;        // 262144
  float* pm     = ws;  ws += BB * NS3;               // 2048
  float* pz     = ws;  ws += BB * NS3;               // 2048
  float* pP     = ws;  ws += (size_t)BB * NS3 * DD;  // 524288

  k1_xsum_part<<<dim3(NS1, BB), 256, 0, stream>>>(x, part);
  k2_prep<<<BB, 1024, 0, stream>>>(part, Wq, bq, Wk, bk, v, c);
  k3_main<<<dim3(NS3, BB), 256, 0, stream>>>(x, v, c, scores, pm, pz, pP);
  k45_final<<<BB + NN / 256, 256, 0, stream>>>(pm, pz, pP, scores, agg, avgw);
}

// Round 12
// 109.022 us; speedup vs baseline: 1.0960x; 1.0272x over previous
//
#include <hip/hip_runtime.h>
#include <math.h>

// Problem shapes (fixed by setup_inputs)
#define BB 16
#define NN 16384
#define DD 256     // == O
#define NS1 128    // blocks per batch, pass 1 (xsum)
#define NS3 128    // blocks per batch, pass 2 (scores + flash partials)

typedef float floatx4 __attribute__((ext_vector_type(4)));

__device__ __forceinline__ floatx4 ntload4(const float* p) {
  return __builtin_nontemporal_load((const floatx4*)p);
}

// ---------------- K1: partial column-sums of x ----------------
// grid (NS1, BB), block 256 (4 waves). Wave w takes rows w, w+4, ... (proven
// traversal) — 8 independent accumulators => 8 NT loads in flight per wave.
__global__ __launch_bounds__(256) void k1_xsum_part(const float* __restrict__ x,
                                                    float* __restrict__ part) {
  const int b = blockIdx.y, blk = blockIdx.x;
  const int wave = threadIdx.x >> 6, lane = threadIdx.x & 63;
  const int rows = NN / NS1;  // 128
  const float* xp = x + ((size_t)b * NN + (size_t)blk * rows + wave) * DD + lane * 4;
  floatx4 a0 = {0.f, 0.f, 0.f, 0.f}, a1 = a0, a2 = a0, a3 = a0;
  floatx4 a4 = a0, a5 = a0, a6 = a0, a7 = a0;
#pragma unroll
  for (int r = 0; r < rows; r += 32) {  // wave's rows: wave + {0,4,...,28} + 32k
    a0 += ntload4(xp + (size_t)(r + 0) * DD);
    a1 += ntload4(xp + (size_t)(r + 4) * DD);
    a2 += ntload4(xp + (size_t)(r + 8) * DD);
    a3 += ntload4(xp + (size_t)(r + 12) * DD);
    a4 += ntload4(xp + (size_t)(r + 16) * DD);
    a5 += ntload4(xp + (size_t)(r + 20) * DD);
    a6 += ntload4(xp + (size_t)(r + 24) * DD);
    a7 += ntload4(xp + (size_t)(r + 28) * DD);
  }
  const floatx4 acc = ((a0 + a1) + (a2 + a3)) + ((a4 + a5) + (a6 + a7));
  __shared__ float sP[4][DD];
  *(floatx4*)&sP[wave][lane * 4] = acc;
  __syncthreads();
  const int t = threadIdx.x;
  part[((size_t)b * NS1 + blk) * DD + t] = sP[0][t] + sP[1][t] + sP[2][t] + sP[3][t];
}

// ---------------- K2: part -> xsum -> ksum -> v, c (1024 threads) ----------
__global__ __launch_bounds__(1024) void k2_prep(const float* __restrict__ part,
                                                const float* __restrict__ Wq,
                                                const float* __restrict__ bq,
                                                const float* __restrict__ Wk,
                                                const float* __restrict__ bk,
                                                float* __restrict__ v,
                                                float* __restrict__ c) {
  const int b = blockIdx.x, t = threadIdx.x;
  const int d = t & 255;   // doubles as output index o
  const int g = t >> 8;    // 0..3
  __shared__ float stage[4][DD];
  __shared__ float xs[DD];
  __shared__ float ks[DD];
  __shared__ float red[256];

  // ---- part walk: tiles [g*32, g*32+32), 8 accumulators ----
  const float* pb = part + (size_t)b * NS1 * DD + d;
  float a[8];
#pragma unroll
  for (int u = 0; u < 8; ++u) a[u] = 0.f;
#pragma unroll
  for (int blk = 0; blk < 32; blk += 8) {
#pragma unroll
    for (int u = 0; u < 8; ++u) a[u] += pb[(size_t)(g * 32 + blk + u) * DD];
  }
  stage[g][d] = ((a[0] + a[1]) + (a[2] + a[3])) + ((a[4] + a[5]) + (a[6] + a[7]));
  __syncthreads();
  if (g == 0) xs[d] = (stage[0][d] + stage[1][d]) + (stage[2][d] + stage[3][d]);
  __syncthreads();

  // ---- ksum[o] partials: group g covers j in [g*64, g*64+64) ----
  float kp = 0.f;
  const float4* wk4 = (const float4*)(Wk + (size_t)d * DD + g * 64);
#pragma unroll 4
  for (int j4 = 0; j4 < 16; ++j4) {
    const float4 w = wk4[j4];
    const int j = g * 64 + 4 * j4;
    kp += w.x * xs[j] + w.y * xs[j + 1] + w.z * xs[j + 2] + w.w * xs[j + 3];
  }
  stage[g][d] = kp;
  __syncthreads();
  if (g == 0)
    ks[d] = (stage[0][d] + stage[1][d]) + (stage[2][d] + stage[3][d]) + (float)NN * bk[d];
  __syncthreads();

  // ---- v[d] partials: group g covers o in [g*64, g*64+64) ----
  float vp = 0.f;
#pragma unroll 4
  for (int o = 0; o < 64; ++o)
    vp += Wq[(size_t)(g * 64 + o) * DD + d] * ks[g * 64 + o];
  stage[g][d] = vp;
  __syncthreads();
  if (g == 0) {
    v[b * DD + d] = (stage[0][d] + stage[1][d]) + (stage[2][d] + stage[3][d]);
    red[d] = bq[d] * ks[d];
  }
  __syncthreads();
  for (int s = 128; s > 0; s >>= 1) {
    if (t < s) red[t] += red[t + s];
    __syncthreads();
  }
  if (t == 0) c[b] = red[0];
}

// ---------------- K3: main pass — 8-row batched flash ----------------
__global__ __launch_bounds__(256) void k3_main(const float* __restrict__ x,
                                               const float* __restrict__ v,
                                               const float* __restrict__ c,
                                               float* __restrict__ scores,
                                               float* __restrict__ pm,
                                               float* __restrict__ pz,
                                               float* __restrict__ pP) {
  const int b = blockIdx.y, blk = blockIdx.x;
  const int wave = threadIdx.x >> 6, lane = threadIdx.x & 63;
  const float scale = 0.0625f;  // 1/sqrt(256)

  const floatx4 vl = *(const floatx4*)(v + b * DD + lane * 4);
  const float cb = c[b];
  const int rows_per_block = NN / NS3;          // 128
  const int rows_per_wave = rows_per_block / 4; // 32
  const int n0 = blk * rows_per_block + wave * rows_per_wave;
  const float* xb = x + (size_t)b * NN * DD;

  float m = -INFINITY, Z = 0.f;
  floatx4 P = {0.f, 0.f, 0.f, 0.f};

#define DOT_OF(XR) ({ const floatx4 _p = (XR) * vl; _p.x + _p.y + _p.z + _p.w; })

  for (int i = 0; i < rows_per_wave; i += 8) {
    const float* base = xb + (size_t)(n0 + i) * DD + lane * 4;
    const floatx4 xr0 = ntload4(base);
    const floatx4 xr1 = ntload4(base + DD);
    const floatx4 xr2 = ntload4(base + 2 * DD);
    const floatx4 xr3 = ntload4(base + 3 * DD);
    const floatx4 xr4 = ntload4(base + 4 * DD);
    const floatx4 xr5 = ntload4(base + 5 * DD);
    const floatx4 xr6 = ntload4(base + 6 * DD);
    const floatx4 xr7 = ntload4(base + 7 * DD);
    float d0 = DOT_OF(xr0), d1 = DOT_OF(xr1), d2 = DOT_OF(xr2), d3 = DOT_OF(xr3);
    float d4 = DOT_OF(xr4), d5 = DOT_OF(xr5), d6 = DOT_OF(xr6), d7 = DOT_OF(xr7);
#pragma unroll
    for (int off = 32; off >= 1; off >>= 1) {  // 8 independent butterfly chains
      d0 += __shfl_xor(d0, off, 64);
      d1 += __shfl_xor(d1, off, 64);
      d2 += __shfl_xor(d2, off, 64);
      d3 += __shfl_xor(d3, off, 64);
      d4 += __shfl_xor(d4, off, 64);
      d5 += __shfl_xor(d5, off, 64);
      d6 += __shfl_xor(d6, off, 64);
      d7 += __shfl_xor(d7, off, 64);
    }
    const float s0 = (d0 + cb) * scale, s1 = (d1 + cb) * scale;
    const float s2 = (d2 + cb) * scale, s3 = (d3 + cb) * scale;
    const float s4 = (d4 + cb) * scale, s5 = (d5 + cb) * scale;
    const float s6 = (d6 + cb) * scale, s7 = (d7 + cb) * scale;
    if (lane == 0) {
      floatx4 sva = {s0, s1, s2, s3};
      floatx4 svb = {s4, s5, s6, s7};
      *(floatx4*)(scores + (size_t)b * NN + n0 + i) = sva;
      *(floatx4*)(scores + (size_t)b * NN + n0 + i + 4) = svb;
    }
    // sequential online-softmax updates (wave-uniform branches)
#define SM_UPDATE(S, XR)                                   \
    if ((S) > m) {                                         \
      const float alpha = __expf(m - (S));                 \
      Z = Z * alpha + 1.f;                                 \
      P = P * alpha + (XR);                                \
      m = (S);                                             \
    } else {                                               \
      const float e = __expf((S) - m);                     \
      Z += e;                                              \
      P += (XR) * e;                                       \
    }
    SM_UPDATE(s0, xr0)
    SM_UPDATE(s1, xr1)
    SM_UPDATE(s2, xr2)
    SM_UPDATE(s3, xr3)
    SM_UPDATE(s4, xr4)
    SM_UPDATE(s5, xr5)
    SM_UPDATE(s6, xr6)
    SM_UPDATE(s7, xr7)
#undef SM_UPDATE
  }

  // combine the 4 waves of this block
  __shared__ float sm[4], sz[4];
  __shared__ float sP[4][DD];
  *(floatx4*)&sP[wave][lane * 4] = P;
  if (lane == 0) { sm[wave] = m; sz[wave] = Z; }
  __syncthreads();

  const int t = threadIdx.x;
  const float M = fmaxf(fmaxf(sm[0], sm[1]), fmaxf(sm[2], sm[3]));
  const float e0 = __expf(sm[0] - M), e1 = __expf(sm[1] - M);
  const float e2 = __expf(sm[2] - M), e3 = __expf(sm[3] - M);
  const float Pd = sP[0][t] * e0 + sP[1][t] * e1 + sP[2][t] * e2 + sP[3][t] * e3;
  const size_t idx = (size_t)b * NS3 + blk;
  pP[idx * DD + t] = Pd;
  if (t == 0) {
    pm[idx] = M;
    pz[idx] = sz[0] * e0 + sz[1] * e1 + sz[2] * e2 + sz[3] * e3;
  }
}

// ---------------- K45: merged finalization ----------------
__global__ __launch_bounds__(256) void k45_final(const float* __restrict__ pm,
                                                 const float* __restrict__ pz,
                                                 const float* __restrict__ pP,
                                                 const float* __restrict__ scores,
                                                 float* __restrict__ out_agg,
                                                 float* __restrict__ out_w) {
  const int t = threadIdx.x;
  if (blockIdx.x < BB) {
    // ---- role A: aggregated_feature[b] ----
    const int b = blockIdx.x;
    __shared__ float red[256];
    __shared__ float sw[NS3];
    const size_t base = (size_t)b * NS3;

    red[t] = (t < NS3) ? pm[base + t] : -INFINITY;
    __syncthreads();
    for (int s = 128; s > 0; s >>= 1) {
      if (t < s) red[t] = fmaxf(red[t], red[t + s]);
      __syncthreads();
    }
    const float M = red[0];
    __syncthreads();

    const float w_t = (t < NS3) ? __expf(pm[base + t] - M) : 0.f;
    if (t < NS3) sw[t] = w_t;
    red[t] = (t < NS3) ? pz[base + t] * w_t : 0.f;
    __syncthreads();
    for (int s = 128; s > 0; s >>= 1) {
      if (t < s) red[t] += red[t + s];
      __syncthreads();
    }
    const float rZ = 1.f / red[0];

    // 4-accumulator unroll of the 128-tile pP walk
    float a0 = 0.f, a1 = 0.f, a2 = 0.f, a3 = 0.f;
    const float* pb = pP + base * DD + t;
#pragma unroll 8
    for (int blk = 0; blk < NS3; blk += 4) {
      a0 += pb[(size_t)(blk + 0) * DD] * sw[blk + 0];
      a1 += pb[(size_t)(blk + 1) * DD] * sw[blk + 1];
      a2 += pb[(size_t)(blk + 2) * DD] * sw[blk + 2];
      a3 += pb[(size_t)(blk + 3) * DD] * sw[blk + 3];
    }
    out_agg[b * DD + t] = ((a0 + a1) + (a2 + a3)) * rZ;
  } else {
    // ---- role B: average_customer_weights ----
    const int wb = blockIdx.x - BB;
    __shared__ float sM[BB], sR[BB];
    const int b = t >> 4;
    const int i = t & 15;
    const size_t base = (size_t)b * NS3 + i * 8;

    float mloc = -INFINITY;
#pragma unroll
    for (int k = 0; k < 8; ++k) mloc = fmaxf(mloc, pm[base + k]);
#pragma unroll
    for (int off = 8; off >= 1; off >>= 1) mloc = fmaxf(mloc, __shfl_xor(mloc, off, 64));
    const float M = mloc;

    float zloc = 0.f;
#pragma unroll
    for (int k = 0; k < 8; ++k) zloc += pz[base + k] * __expf(pm[base + k] - M);
#pragma unroll
    for (int off = 8; off >= 1; off >>= 1) zloc += __shfl_xor(zloc, off, 64);

    if (i == 0) { sM[b] = M; sR[b] = 1.f / zloc; }
    __syncthreads();

    const int n = wb * 256 + t;
    float acc = 0.f;
#pragma unroll
    for (int bb = 0; bb < BB; ++bb)
      acc += __expf(scores[(size_t)bb * NN + n] - sM[bb]) * sR[bb];
    out_w[n] = acc * (1.f / BB);
  }
}

extern "C" void kernel_launch(void* const* d_in, const int* in_sizes, int n_in,
                              void* d_out, int out_size, void* d_ws, size_t ws_size,
                              hipStream_t stream) {
  const float* x  = (const float*)d_in[0];
  const float* Wq = (const float*)d_in[1];
  const float* bq = (const float*)d_in[2];
  const float* Wk = (const float*)d_in[3];
  const float* bk = (const float*)d_in[4];

  float* out  = (float*)d_out;
  float* agg  = out;             // [16, 256]
  float* avgw = out + BB * DD;   // [16384]

  float* ws = (float*)d_ws;
  float* part   = ws;  ws += (size_t)BB * NS1 * DD;  // 524288
  float* v      = ws;  ws += BB * DD;                // 4096
  float* c      = ws;  ws += BB;                     // 16
  float* scores = ws;  ws += (size_t)BB * NN;        // 262144
  float* pm     = ws;  ws += BB * NS3;               // 2048
  float* pz     = ws;  ws += BB * NS3;               // 2048
  float* pP     = ws;  ws += (size_t)BB * NS3 * DD;  // 524288

  k1_xsum_part<<<dim3(NS1, BB), 256, 0, stream>>>(x, part);
  k2_prep<<<BB, 1024, 0, stream>>>(part, Wq, bq, Wk, bk, v, c);
  k3_main<<<dim3(NS3, BB), 256, 0, stream>>>(x, v, c, scores, pm, pz, pP);
  k45_final<<<BB + NN / 256, 256, 0, stream>>>(pm, pz, pP, scores, agg, avgw);
}